// Round 5
// baseline (2337.924 us; speedup 1.0000x reference)
//
#include <hip/hip_runtime.h>
#include <hip/hip_bf16.h>

#define D 48
#define GNUM 64
#define HDIM 128
#define ODIM 12
#define BN_EPS 1e-5f
// Features stored as 3 chunk-planes of 16 features (32 B/node/plane, 3.2 MB/plane):
// addr(node i, chunk c, off o) = c*PS + i*16 + o, PS = N*16.

typedef _Float16 half2v __attribute__((ext_vector_type(2)));
typedef _Float16 half4v __attribute__((ext_vector_type(4)));
typedef _Float16 half8v __attribute__((ext_vector_type(8)));

#if __has_builtin(__builtin_amdgcn_fdot2)
#define FDOT2(a, b, c) __builtin_amdgcn_fdot2((a), (b), (c), false)
#else
#define FDOT2(a, b, c) ((c) + (float)(a)[0] * (float)(b)[0] + (float)(a)[1] * (float)(b)[1])
#endif

// ---------------- setup kernels ----------------

__global__ __launch_bounds__(256) void k_deg(const int* __restrict__ row, int* __restrict__ deg, int E) {
    int e = blockIdx.x * 256 + threadIdx.x;
    if (e < E) atomicAdd(&deg[row[e]], 1);
}

__global__ __launch_bounds__(256) void k_dinv(const int* __restrict__ deg, float* __restrict__ dinv, int N) {
    int i = blockIdx.x * 256 + threadIdx.x;
    if (i < N) dinv[i] = deg[i] > 0 ? rsqrtf((float)deg[i]) : 0.f;
}

__global__ __launch_bounds__(256) void k_scan1(const int* __restrict__ deg, int* __restrict__ incl,
                                               int* __restrict__ bsum, int N) {
    __shared__ int s[256];
    int i = blockIdx.x * 256 + threadIdx.x;
    s[threadIdx.x] = (i < N) ? deg[i] : 0;
    __syncthreads();
    for (int off = 1; off < 256; off <<= 1) {
        int t = (threadIdx.x >= off) ? s[threadIdx.x - off] : 0;
        __syncthreads();
        s[threadIdx.x] += t;
        __syncthreads();
    }
    if (i < N) incl[i] = s[threadIdx.x];
    if (threadIdx.x == 255) bsum[blockIdx.x] = s[255];
}

__global__ __launch_bounds__(512) void k_scan2(int* __restrict__ bsum, int nb) {
    __shared__ int s[512];
    int t = threadIdx.x;
    s[t] = (t < nb) ? bsum[t] : 0;
    __syncthreads();
    for (int off = 1; off < 512; off <<= 1) {
        int v = (t >= off) ? s[t - off] : 0;
        __syncthreads();
        s[t] += v;
        __syncthreads();
    }
    if (t < nb) bsum[t] = s[t];
}

__global__ __launch_bounds__(256) void k_scan3(const int* __restrict__ incl, const int* __restrict__ bsum,
                                               int* __restrict__ rowptr, int N) {
    int i = blockIdx.x * 256 + threadIdx.x;
    if (i < N) {
        int add = (blockIdx.x > 0) ? bsum[blockIdx.x - 1] : 0;
        rowptr[i + 1] = incl[i] + add;
    }
    if (i == 0) rowptr[0] = 0;
}

__global__ __launch_bounds__(256) void k_fill(const int* __restrict__ row, const int* __restrict__ col,
                                              const int* __restrict__ rowptr, int* __restrict__ fillc,
                                              int* __restrict__ ecol, int E) {
    int e = blockIdx.x * 256 + threadIdx.x;
    if (e < E) {
        int r = row[e], c = col[e];
        int p = rowptr[r] + atomicAdd(&fillc[r], 1);
        ecol[p] = c;
    }
}

// xh = fp16(x); xs = fp16(dinv*x); both in plane layout
__global__ __launch_bounds__(256) void k_cvt(const float* __restrict__ x, const float* __restrict__ dinv,
                                             _Float16* __restrict__ xh, _Float16* __restrict__ xs,
                                             int n4, size_t PS) {
    int i = blockIdx.x * 256 + threadIdx.x;
    if (i < n4) {
        int node = i / 12, fb = i % 12;
        size_t dst = (size_t)(fb >> 2) * PS + (size_t)node * 16 + (fb & 3) * 4;
        float dv = dinv[node];
        float4 v = ((const float4*)x)[i];
        half4v h, hs;
        h.x = (_Float16)v.x; h.y = (_Float16)v.y; h.z = (_Float16)v.z; h.w = (_Float16)v.w;
        hs.x = (_Float16)(dv * v.x); hs.y = (_Float16)(dv * v.y);
        hs.z = (_Float16)(dv * v.z); hs.w = (_Float16)(dv * v.w);
        *(half4v*)(xh + dst) = h;
        *(half4v*)(xs + dst) = hs;
    }
}

// ---------------- gather kernels (per chunk plane) ----------------
// wave per node; 16 slots x 4 lanes; q=lane&3 covers features 4q..4q+3 of chunk; unroll x2.

// tx1 = -dinv[i] * sum(curs[c]); tx1s = dinv[i] * tx1   (chunk plane cc)
__global__ __launch_bounds__(256) void k_lhat(const _Float16* __restrict__ curs, const int* __restrict__ rowptr,
                                              const int* __restrict__ ecol, const float* __restrict__ dinv,
                                              _Float16* __restrict__ tx1, _Float16* __restrict__ tx1s,
                                              int N, int cc, size_t PS) {
    int lane = threadIdx.x & 63;
    int i = (blockIdx.x * 256 + threadIdx.x) >> 6;
    if (i >= N) return;
    int q = lane & 3, slot = lane >> 2;
    const _Float16* plane = curs + (size_t)cc * PS;
    int s = rowptr[i], e = rowptr[i + 1];
    float a0 = 0.f, a1 = 0.f, a2 = 0.f, a3 = 0.f;
    int p = s + slot;
    for (; p + 16 < e; p += 32) {
        int ca = __builtin_nontemporal_load(ecol + p);
        int cb = __builtin_nontemporal_load(ecol + p + 16);
        half4v ha = *(const half4v*)(plane + (size_t)ca * 16 + q * 4);
        half4v hb = *(const half4v*)(plane + (size_t)cb * 16 + q * 4);
        a0 += (float)ha.x + (float)hb.x; a1 += (float)ha.y + (float)hb.y;
        a2 += (float)ha.z + (float)hb.z; a3 += (float)ha.w + (float)hb.w;
    }
    if (p < e) {
        int ca = __builtin_nontemporal_load(ecol + p);
        half4v ha = *(const half4v*)(plane + (size_t)ca * 16 + q * 4);
        a0 += (float)ha.x; a1 += (float)ha.y; a2 += (float)ha.z; a3 += (float)ha.w;
    }
#pragma unroll
    for (int m = 4; m <= 32; m <<= 1) {
        a0 += __shfl_xor(a0, m); a1 += __shfl_xor(a1, m);
        a2 += __shfl_xor(a2, m); a3 += __shfl_xor(a3, m);
    }
    if (slot == 0) {
        float di = dinv[i];
        size_t dst = (size_t)cc * PS + (size_t)i * 16 + q * 4;
        half4v o, os;
        float t0 = -di * a0, t1 = -di * a1, t2 = -di * a2, t3 = -di * a3;
        o.x = (_Float16)t0; o.y = (_Float16)t1; o.z = (_Float16)t2; o.w = (_Float16)t3;
        os.x = (_Float16)(di * t0); os.y = (_Float16)(di * t1);
        os.z = (_Float16)(di * t2); os.w = (_Float16)(di * t3);
        *(half4v*)(tx1 + dst) = o;
        *(half4v*)(tx1s + dst) = os;
    }
}

// tx2 = -2*dinv[i] * sum(tx1s[c]) - tx0   (chunk plane cc)
__global__ __launch_bounds__(256) void k_gather2(const _Float16* __restrict__ tx0, const _Float16* __restrict__ tx1s,
                                                 const int* __restrict__ rowptr, const int* __restrict__ ecol,
                                                 const float* __restrict__ dinv, _Float16* __restrict__ tx2,
                                                 int N, int cc, size_t PS) {
    int lane = threadIdx.x & 63;
    int i = (blockIdx.x * 256 + threadIdx.x) >> 6;
    if (i >= N) return;
    int q = lane & 3, slot = lane >> 2;
    const _Float16* plane = tx1s + (size_t)cc * PS;
    int s = rowptr[i], e = rowptr[i + 1];
    float a0 = 0.f, a1 = 0.f, a2 = 0.f, a3 = 0.f;
    int p = s + slot;
    for (; p + 16 < e; p += 32) {
        int ca = __builtin_nontemporal_load(ecol + p);
        int cb = __builtin_nontemporal_load(ecol + p + 16);
        half4v ha = *(const half4v*)(plane + (size_t)ca * 16 + q * 4);
        half4v hb = *(const half4v*)(plane + (size_t)cb * 16 + q * 4);
        a0 += (float)ha.x + (float)hb.x; a1 += (float)ha.y + (float)hb.y;
        a2 += (float)ha.z + (float)hb.z; a3 += (float)ha.w + (float)hb.w;
    }
    if (p < e) {
        int ca = __builtin_nontemporal_load(ecol + p);
        half4v ha = *(const half4v*)(plane + (size_t)ca * 16 + q * 4);
        a0 += (float)ha.x; a1 += (float)ha.y; a2 += (float)ha.z; a3 += (float)ha.w;
    }
#pragma unroll
    for (int m = 4; m <= 32; m <<= 1) {
        a0 += __shfl_xor(a0, m); a1 += __shfl_xor(a1, m);
        a2 += __shfl_xor(a2, m); a3 += __shfl_xor(a3, m);
    }
    if (slot == 0) {
        float sc = -2.f * dinv[i];
        size_t dst = (size_t)cc * PS + (size_t)i * 16 + q * 4;
        half4v h0 = *(const half4v*)(tx0 + dst);
        half4v o;
        o.x = (_Float16)(sc * a0 - (float)h0.x); o.y = (_Float16)(sc * a1 - (float)h0.y);
        o.z = (_Float16)(sc * a2 - (float)h0.z); o.w = (_Float16)(sc * a3 - (float)h0.w);
        *(half4v*)(tx2 + dst) = o;
    }
}

// ---------------- dense: t = relu([tx0|tx1|tx2] @ W + b) ----------------

__global__ __launch_bounds__(256) void k_dense(const _Float16* __restrict__ tx0, const _Float16* __restrict__ tx1,
                                               const _Float16* __restrict__ tx2, const float* __restrict__ W,
                                               const float* __restrict__ b, _Float16* __restrict__ tbuf,
                                               int N, size_t PS) {
    __shared__ half2v WH2[72 * D];  // [kp][j] = (W[2kp][j], W[2kp+1][j]); 13824 B
    __shared__ float bL[D];
    for (int t = threadIdx.x; t < 72 * D; t += 256) {
        int kp = t / D, j = t % D;
        half2v w;
        w.x = (_Float16)W[(2 * kp) * D + j];
        w.y = (_Float16)W[(2 * kp + 1) * D + j];
        WH2[t] = w;
    }
    if (threadIdx.x < D) bL[threadIdx.x] = b[threadIdx.x];
    __syncthreads();

    int base = (blockIdx.x * 256 + threadIdx.x) * 2;
    if (base >= N) return;
    bool two = (base + 1) < N;
    int base2 = two ? base + 1 : base;

    const _Float16* srcs[3] = {tx0, tx1, tx2};

    float acc0[D], acc1[D];
#pragma unroll
    for (int j = 0; j < D; ++j) { acc0[j] = bL[j]; acc1[j] = bL[j]; }

    for (int s = 0; s < 3; ++s) {
        const _Float16* tp = srcs[s];
        for (int c = 0; c < 3; ++c) {
            const half2v* xa = (const half2v*)(tp + (size_t)c * PS + (size_t)base * 16);
            const half2v* xb = (const half2v*)(tp + (size_t)c * PS + (size_t)base2 * 16);
#pragma unroll
            for (int gg = 0; gg < 8; ++gg) {
                half2v va = xa[gg], vb = xb[gg];
                int kp = s * 24 + c * 8 + gg;
                const half8v* wr = (const half8v*)&WH2[kp * D];
#pragma unroll
                for (int jc = 0; jc < 12; ++jc) {
                    half8v w = wr[jc];
                    half2v w0; w0.x = w[0]; w0.y = w[1];
                    half2v w1; w1.x = w[2]; w1.y = w[3];
                    half2v w2; w2.x = w[4]; w2.y = w[5];
                    half2v w3; w3.x = w[6]; w3.y = w[7];
                    acc0[jc * 4 + 0] = FDOT2(va, w0, acc0[jc * 4 + 0]);
                    acc0[jc * 4 + 1] = FDOT2(va, w1, acc0[jc * 4 + 1]);
                    acc0[jc * 4 + 2] = FDOT2(va, w2, acc0[jc * 4 + 2]);
                    acc0[jc * 4 + 3] = FDOT2(va, w3, acc0[jc * 4 + 3]);
                    acc1[jc * 4 + 0] = FDOT2(vb, w0, acc1[jc * 4 + 0]);
                    acc1[jc * 4 + 1] = FDOT2(vb, w1, acc1[jc * 4 + 1]);
                    acc1[jc * 4 + 2] = FDOT2(vb, w2, acc1[jc * 4 + 2]);
                    acc1[jc * 4 + 3] = FDOT2(vb, w3, acc1[jc * 4 + 3]);
                }
            }
        }
    }

#pragma unroll
    for (int jc = 0; jc < 12; ++jc) {
        size_t dst = (size_t)(jc >> 2) * PS + (size_t)base * 16 + (jc & 3) * 4;
        half4v h;
        h.x = (_Float16)fmaxf(acc0[jc * 4 + 0], 0.f);
        h.y = (_Float16)fmaxf(acc0[jc * 4 + 1], 0.f);
        h.z = (_Float16)fmaxf(acc0[jc * 4 + 2], 0.f);
        h.w = (_Float16)fmaxf(acc0[jc * 4 + 3], 0.f);
        *(half4v*)(tbuf + dst) = h;
    }
    if (two) {
#pragma unroll
        for (int jc = 0; jc < 12; ++jc) {
            size_t dst = (size_t)(jc >> 2) * PS + (size_t)(base + 1) * 16 + (jc & 3) * 4;
            half4v h;
            h.x = (_Float16)fmaxf(acc1[jc * 4 + 0], 0.f);
            h.y = (_Float16)fmaxf(acc1[jc * 4 + 1], 0.f);
            h.z = (_Float16)fmaxf(acc1[jc * 4 + 2], 0.f);
            h.w = (_Float16)fmaxf(acc1[jc * 4 + 3], 0.f);
            *(half4v*)(tbuf + dst) = h;
        }
    }
}

// ---------------- BN stats / finalize ----------------

__global__ __launch_bounds__(256) void k_bnstat(const _Float16* __restrict__ tbuf, float* __restrict__ bnstats,
                                                int N, size_t PS) {
    __shared__ float red[2 * D];
    if (threadIdx.x < 2 * D) red[threadIdx.x] = 0.f;
    __syncthreads();
    int tid = blockIdx.x * 256 + threadIdx.x;
    int q = tid % 12;
    int n0 = tid / 12;
    int stride = (gridDim.x * 256) / 12;
    size_t poff = (size_t)(q >> 2) * PS + (q & 3) * 4;
    float s0 = 0, s1 = 0, s2 = 0, s3 = 0, q0 = 0, q1 = 0, q2 = 0, q3 = 0;
    for (int n = n0; n < N; n += stride) {
        half4v h = *(const half4v*)(tbuf + poff + (size_t)n * 16);
        float f0 = (float)h.x, f1 = (float)h.y, f2 = (float)h.z, f3 = (float)h.w;
        s0 += f0; s1 += f1; s2 += f2; s3 += f3;
        q0 += f0 * f0; q1 += f1 * f1; q2 += f2 * f2; q3 += f3 * f3;
    }
    atomicAdd(&red[q * 4 + 0], s0); atomicAdd(&red[q * 4 + 1], s1);
    atomicAdd(&red[q * 4 + 2], s2); atomicAdd(&red[q * 4 + 3], s3);
    atomicAdd(&red[D + q * 4 + 0], q0); atomicAdd(&red[D + q * 4 + 1], q1);
    atomicAdd(&red[D + q * 4 + 2], q2); atomicAdd(&red[D + q * 4 + 3], q3);
    __syncthreads();
    if (threadIdx.x < 2 * D) atomicAdd(&bnstats[threadIdx.x], red[threadIdx.x]);
}

__global__ __launch_bounds__(64) void k_bnfin(float* __restrict__ bnstats, const float* __restrict__ gamma,
                                              const float* __restrict__ beta, float* __restrict__ ss, float Ninv) {
    int t = threadIdx.x;
    if (t < D) {
        float mean = bnstats[t] * Ninv;
        float var = bnstats[D + t] * Ninv - mean * mean;
        var = fmaxf(var, 0.f);
        float sc = gamma[t] * rsqrtf(var + BN_EPS);
        ss[t] = sc;
        ss[D + t] = beta[t] - mean * sc;
        bnstats[t] = 0.f;
        bnstats[D + t] = 0.f;
    }
}

// ---------------- pool (per chunk plane) ----------------

__global__ __launch_bounds__(256) void k_pool(const _Float16* __restrict__ tbuf, const int* __restrict__ rowptr,
                                              const int* __restrict__ ecol, const float* __restrict__ ss,
                                              const float* __restrict__ dinv, _Float16* __restrict__ outh,
                                              _Float16* __restrict__ outs, int N, int cc, size_t PS) {
    int lane = threadIdx.x & 63;
    int i = (blockIdx.x * 256 + threadIdx.x) >> 6;
    if (i >= N) return;
    int q = lane & 3, slot = lane >> 2;
    const _Float16* plane = tbuf + (size_t)cc * PS;
    int s = rowptr[i], e = rowptr[i + 1];
    float m0 = -3.4e38f, m1 = -3.4e38f, m2 = -3.4e38f, m3 = -3.4e38f;
    float n0 = 3.4e38f, n1 = 3.4e38f, n2 = 3.4e38f, n3 = 3.4e38f;
    int p = s + slot;
    for (; p + 16 < e; p += 32) {
        int ca = __builtin_nontemporal_load(ecol + p);
        int cb = __builtin_nontemporal_load(ecol + p + 16);
        half4v ha = *(const half4v*)(plane + (size_t)ca * 16 + q * 4);
        half4v hb = *(const half4v*)(plane + (size_t)cb * 16 + q * 4);
        float fa0 = (float)ha.x, fa1 = (float)ha.y, fa2 = (float)ha.z, fa3 = (float)ha.w;
        float fb0 = (float)hb.x, fb1 = (float)hb.y, fb2 = (float)hb.z, fb3 = (float)hb.w;
        m0 = fmaxf(m0, fmaxf(fa0, fb0)); m1 = fmaxf(m1, fmaxf(fa1, fb1));
        m2 = fmaxf(m2, fmaxf(fa2, fb2)); m3 = fmaxf(m3, fmaxf(fa3, fb3));
        n0 = fminf(n0, fminf(fa0, fb0)); n1 = fminf(n1, fminf(fa1, fb1));
        n2 = fminf(n2, fminf(fa2, fb2)); n3 = fminf(n3, fminf(fa3, fb3));
    }
    if (p < e) {
        int ca = __builtin_nontemporal_load(ecol + p);
        half4v ha = *(const half4v*)(plane + (size_t)ca * 16 + q * 4);
        float fa0 = (float)ha.x, fa1 = (float)ha.y, fa2 = (float)ha.z, fa3 = (float)ha.w;
        m0 = fmaxf(m0, fa0); m1 = fmaxf(m1, fa1); m2 = fmaxf(m2, fa2); m3 = fmaxf(m3, fa3);
        n0 = fminf(n0, fa0); n1 = fminf(n1, fa1); n2 = fminf(n2, fa2); n3 = fminf(n3, fa3);
    }
#pragma unroll
    for (int m = 4; m <= 32; m <<= 1) {
        m0 = fmaxf(m0, __shfl_xor(m0, m)); m1 = fmaxf(m1, __shfl_xor(m1, m));
        m2 = fmaxf(m2, __shfl_xor(m2, m)); m3 = fmaxf(m3, __shfl_xor(m3, m));
        n0 = fminf(n0, __shfl_xor(n0, m)); n1 = fminf(n1, __shfl_xor(n1, m));
        n2 = fminf(n2, __shfl_xor(n2, m)); n3 = fminf(n3, __shfl_xor(n3, m));
    }
    if (slot == 0) {
        size_t dst = (size_t)cc * PS + (size_t)i * 16 + q * 4;
        half4v o, os;
        if (s == e) {
            o.x = o.y = o.z = o.w = (_Float16)0.f;
            os.x = os.y = os.z = os.w = (_Float16)0.f;
        } else {
            float di = dinv[i];
            float4 sc = *(const float4*)(ss + cc * 16 + q * 4);
            float4 sh = *(const float4*)(ss + D + cc * 16 + q * 4);
            float v0 = (sc.x >= 0.f) ? sc.x * m0 + sh.x : sc.x * n0 + sh.x;
            float v1 = (sc.y >= 0.f) ? sc.y * m1 + sh.y : sc.y * n1 + sh.y;
            float v2 = (sc.z >= 0.f) ? sc.z * m2 + sh.z : sc.z * n2 + sh.z;
            float v3 = (sc.w >= 0.f) ? sc.w * m3 + sh.w : sc.w * n3 + sh.w;
            o.x = (_Float16)v0; o.y = (_Float16)v1; o.z = (_Float16)v2; o.w = (_Float16)v3;
            os.x = (_Float16)(di * v0); os.y = (_Float16)(di * v1);
            os.z = (_Float16)(di * v2); os.w = (_Float16)(di * v3);
        }
        *(half4v*)(outh + dst) = o;
        *(half4v*)(outs + dst) = os;
    }
}

// ---------------- final pooling + MLP ----------------

__global__ __launch_bounds__(256) void k_gpool(const _Float16* __restrict__ outh, const int* __restrict__ batch,
                                               float* __restrict__ g, int N, int chunk, size_t PS) {
    int lane = threadIdx.x & 63;
    int wid = (blockIdx.x * 256 + threadIdx.x) >> 6;
    int start = wid * chunk;
    if (start >= N || lane >= 12) return;
    int end = start + chunk;
    if (end > N) end = N;
    size_t poff = (size_t)(lane >> 2) * PS + (lane & 3) * 4;
    int curb = batch[start];
    float a0 = 0.f, a1 = 0.f, a2 = 0.f, a3 = 0.f;
    for (int i = start; i < end; ++i) {
        int bi = batch[i];
        if (bi != curb) {
            atomicAdd(&g[curb * D + lane * 4 + 0], a0); atomicAdd(&g[curb * D + lane * 4 + 1], a1);
            atomicAdd(&g[curb * D + lane * 4 + 2], a2); atomicAdd(&g[curb * D + lane * 4 + 3], a3);
            curb = bi; a0 = a1 = a2 = a3 = 0.f;
        }
        half4v h = *(const half4v*)(outh + poff + (size_t)i * 16);
        a0 += (float)h.x; a1 += (float)h.y; a2 += (float)h.z; a3 += (float)h.w;
    }
    atomicAdd(&g[curb * D + lane * 4 + 0], a0); atomicAdd(&g[curb * D + lane * 4 + 1], a1);
    atomicAdd(&g[curb * D + lane * 4 + 2], a2); atomicAdd(&g[curb * D + lane * 4 + 3], a3);
}

__global__ __launch_bounds__(256) void k_mlp(const float* __restrict__ g, const float* __restrict__ W1,
                                             const float* __restrict__ b1, const float* __restrict__ W2,
                                             const float* __restrict__ b2, float* __restrict__ out) {
    __shared__ float gL[GNUM * D];
    __shared__ float hL[GNUM * HDIM];
    __shared__ float W1L[D * HDIM];
    int t = threadIdx.x;
    for (int i = t; i < GNUM * D; i += 256) gL[i] = g[i];
    for (int i = t; i < D * HDIM; i += 256) W1L[i] = W1[i];
    __syncthreads();
    for (int i = t; i < GNUM * HDIM; i += 256) {
        int gi = i >> 7, hj = i & 127;
        float a = b1[hj];
        for (int k = 0; k < D; ++k) a += gL[gi * D + k] * W1L[k * HDIM + hj];
        hL[i] = fmaxf(a, 0.f);
    }
    __syncthreads();
    for (int i = t; i < GNUM * ODIM; i += 256) {
        int gi = i / ODIM, oj = i % ODIM;
        float a = b2[oj];
        for (int k = 0; k < HDIM; ++k) a += hL[gi * HDIM + k] * W2[k * ODIM + oj];
        out[i] = a;
    }
}

// ---------------- launch ----------------

extern "C" void kernel_launch(void* const* d_in, const int* in_sizes, int n_in,
                              void* d_out, int out_size, void* d_ws, size_t ws_size,
                              hipStream_t stream) {
    const float* x     = (const float*)d_in[0];
    const int*   ei    = (const int*)d_in[1];
    const int*   batch = (const int*)d_in[2];
    const float* W     = (const float*)d_in[4];
    const float* b     = (const float*)d_in[5];
    const float* gamma = (const float*)d_in[6];
    const float* beta  = (const float*)d_in[7];
    const float* W1    = (const float*)d_in[8];
    const float* b1    = (const float*)d_in[9];
    const float* W2    = (const float*)d_in[10];
    const float* b2    = (const float*)d_in[11];

    int N = in_sizes[0] / D;
    int E = in_sizes[1] / 2;
    const int* row = ei;
    const int* col = ei + E;
    size_t PS = (size_t)N * 16;  // plane stride in fp16 elements

    char* w = (char*)d_ws;
    auto alloc = [&](size_t bytes) { char* p = w; w += (bytes + 255) & ~(size_t)255; return p; };
    int*       deg     = (int*)alloc((size_t)N * 4);
    float*     dinv    = (float*)alloc((size_t)N * 4);
    int*       fillc   = (int*)alloc((size_t)N * 4);
    int*       incl    = (int*)alloc((size_t)N * 4);
    int*       bsum    = (int*)alloc(4096);
    int*       rowptr  = (int*)alloc((size_t)(N + 1) * 4);
    int*       ecol    = (int*)alloc((size_t)E * 4);
    _Float16*  xh      = (_Float16*)alloc((size_t)N * D * 2 + 64);
    _Float16*  xs      = (_Float16*)alloc((size_t)N * D * 2 + 64);
    _Float16*  tx1h    = (_Float16*)alloc((size_t)N * D * 2 + 64);
    _Float16*  tx1s    = (_Float16*)alloc((size_t)N * D * 2 + 64);
    _Float16*  tx2h    = (_Float16*)alloc((size_t)N * D * 2 + 64);
    _Float16*  tbufh   = (_Float16*)alloc((size_t)N * D * 2 + 64);
    _Float16*  outh    = (_Float16*)alloc((size_t)N * D * 2 + 64);
    _Float16*  outs    = (_Float16*)alloc((size_t)N * D * 2 + 64);
    float*     bnstats = (float*)alloc(2 * D * 4);
    float*     ss      = (float*)alloc(2 * D * 4);
    float*     g       = (float*)alloc((size_t)GNUM * D * 4);

    hipMemsetAsync(deg, 0, (size_t)N * 4, stream);
    hipMemsetAsync(fillc, 0, (size_t)N * 4, stream);
    hipMemsetAsync(bnstats, 0, 2 * D * 4, stream);
    hipMemsetAsync(g, 0, (size_t)GNUM * D * 4, stream);

    int nbE = (E + 255) / 256;
    int nbN = (N + 255) / 256;

    k_deg<<<nbE, 256, 0, stream>>>(row, deg, E);
    k_dinv<<<nbN, 256, 0, stream>>>(deg, dinv, N);
    k_scan1<<<nbN, 256, 0, stream>>>(deg, incl, bsum, N);
    k_scan2<<<1, 512, 0, stream>>>(bsum, nbN);
    k_scan3<<<nbN, 256, 0, stream>>>(incl, bsum, rowptr, N);
    k_fill<<<nbE, 256, 0, stream>>>(row, col, rowptr, fillc, ecol, E);
    int n4 = N * D / 4;
    k_cvt<<<(n4 + 255) / 256, 256, 0, stream>>>(x, dinv, xh, xs, n4, PS);

    int nbWave = (N * 64 + 255) / 256;
    int nbDense = ((N + 1) / 2 + 255) / 256;
    const _Float16* curh = xh;
    const _Float16* curs = xs;
    for (int step = 0; step < 5; ++step) {
        for (int c = 0; c < 3; ++c)
            k_lhat<<<nbWave, 256, 0, stream>>>(curs, rowptr, ecol, dinv, tx1h, tx1s, N, c, PS);
        for (int c = 0; c < 3; ++c)
            k_gather2<<<nbWave, 256, 0, stream>>>(curh, tx1s, rowptr, ecol, dinv, tx2h, N, c, PS);
        k_dense<<<nbDense, 256, 0, stream>>>(curh, tx1h, tx2h, W, b, tbufh, N, PS);
        k_bnstat<<<120, 256, 0, stream>>>(tbufh, bnstats, N, PS);
        k_bnfin<<<1, 64, 0, stream>>>(bnstats, gamma, beta, ss, 1.f / (float)N);
        for (int c = 0; c < 3; ++c)
            k_pool<<<nbWave, 256, 0, stream>>>(tbufh, rowptr, ecol, ss, dinv, outh, outs, N, c, PS);
        curh = outh;
        curs = outs;
    }

    int chunk = 32;
    int nwaves = (N + chunk - 1) / chunk;
    int nbG = (nwaves * 64 + 255) / 256;
    k_gpool<<<nbG, 256, 0, stream>>>(outh, batch, g, N, chunk, PS);
    k_mlp<<<1, 256, 0, stream>>>(g, W1, b1, W2, b2, (float*)d_out);
}

// Round 6
// 1380.926 us; speedup vs baseline: 1.6930x; 1.6930x over previous
//
#include <hip/hip_runtime.h>
#include <hip/hip_bf16.h>

#define D 48
#define GNUM 64
#define HDIM 128
#define ODIM 12
#define BN_EPS 1e-5f

typedef _Float16 half2v __attribute__((ext_vector_type(2)));
typedef _Float16 half4v __attribute__((ext_vector_type(4)));
typedef _Float16 half8v __attribute__((ext_vector_type(8)));

#if __has_builtin(__builtin_amdgcn_fdot2)
#define FDOT2(a, b, c) __builtin_amdgcn_fdot2((a), (b), (c), false)
#else
#define FDOT2(a, b, c) ((c) + (float)(a)[0] * (float)(b)[0] + (float)(a)[1] * (float)(b)[1])
#endif

// ---------------- setup kernels ----------------

__global__ __launch_bounds__(256) void k_deg(const int* __restrict__ row, int* __restrict__ deg, int E) {
    int e = blockIdx.x * 256 + threadIdx.x;
    if (e < E) atomicAdd(&deg[row[e]], 1);
}

__global__ __launch_bounds__(256) void k_dinv(const int* __restrict__ deg, float* __restrict__ dinv, int N) {
    int i = blockIdx.x * 256 + threadIdx.x;
    if (i < N) dinv[i] = deg[i] > 0 ? rsqrtf((float)deg[i]) : 0.f;
}

__global__ __launch_bounds__(256) void k_scan1(const int* __restrict__ deg, int* __restrict__ incl,
                                               int* __restrict__ bsum, int N) {
    __shared__ int s[256];
    int i = blockIdx.x * 256 + threadIdx.x;
    s[threadIdx.x] = (i < N) ? deg[i] : 0;
    __syncthreads();
    for (int off = 1; off < 256; off <<= 1) {
        int t = (threadIdx.x >= off) ? s[threadIdx.x - off] : 0;
        __syncthreads();
        s[threadIdx.x] += t;
        __syncthreads();
    }
    if (i < N) incl[i] = s[threadIdx.x];
    if (threadIdx.x == 255) bsum[blockIdx.x] = s[255];
}

__global__ __launch_bounds__(512) void k_scan2(int* __restrict__ bsum, int nb) {
    __shared__ int s[512];
    int t = threadIdx.x;
    s[t] = (t < nb) ? bsum[t] : 0;
    __syncthreads();
    for (int off = 1; off < 512; off <<= 1) {
        int v = (t >= off) ? s[t - off] : 0;
        __syncthreads();
        s[t] += v;
        __syncthreads();
    }
    if (t < nb) bsum[t] = s[t];
}

__global__ __launch_bounds__(256) void k_scan3(const int* __restrict__ incl, const int* __restrict__ bsum,
                                               int* __restrict__ rowptr, int N) {
    int i = blockIdx.x * 256 + threadIdx.x;
    if (i < N) {
        int add = (blockIdx.x > 0) ? bsum[blockIdx.x - 1] : 0;
        rowptr[i + 1] = incl[i] + add;
    }
    if (i == 0) rowptr[0] = 0;
}

__global__ __launch_bounds__(256) void k_fill(const int* __restrict__ row, const int* __restrict__ col,
                                              const int* __restrict__ rowptr, int* __restrict__ fillc,
                                              int* __restrict__ ecol, int E) {
    int e = blockIdx.x * 256 + threadIdx.x;
    if (e < E) {
        int r = row[e], c = col[e];
        int p = rowptr[r] + atomicAdd(&fillc[r], 1);
        __builtin_nontemporal_store(c, ecol + p);
    }
}

// xh = fp16(x); xs = fp16(dinv[node] * x)
__global__ __launch_bounds__(256) void k_cvt(const float* __restrict__ x, const float* __restrict__ dinv,
                                             _Float16* __restrict__ xh, _Float16* __restrict__ xs, int n4) {
    int i = blockIdx.x * 256 + threadIdx.x;
    if (i < n4) {
        int node = i / 12;  // D/4 chunks per node
        float dv = dinv[node];
        float4 v = ((const float4*)x)[i];
        half4v h, hs;
        h.x = (_Float16)v.x; h.y = (_Float16)v.y; h.z = (_Float16)v.z; h.w = (_Float16)v.w;
        hs.x = (_Float16)(dv * v.x); hs.y = (_Float16)(dv * v.y);
        hs.z = (_Float16)(dv * v.z); hs.w = (_Float16)(dv * v.w);
        ((half4v*)xh)[i] = h;
        ((half4v*)xs)[i] = hs;
    }
}

// ---------------- gather kernels ----------------
// 2 nodes per wave; 8 slots x 8 lanes; q<6 active (6 x 16B = 96B row).
// Main loop issues 4 independent 16B gathers (2 per node) before accumulating.

// tx1 = -dinv[i] * sum(curs[c]); tx1s = dinv[i] * tx1
__global__ __launch_bounds__(256) void k_lhat(const _Float16* __restrict__ curs, const int* __restrict__ rowptr,
                                              const int* __restrict__ ecol, const float* __restrict__ dinv,
                                              _Float16* __restrict__ tx1, _Float16* __restrict__ tx1s, int N) {
    int lane = threadIdx.x & 63;
    int wv = (blockIdx.x * 256 + threadIdx.x) >> 6;
    int i0 = wv * 2;
    if (i0 >= N) return;
    int i1 = i0 + 1;
    bool has1 = i1 < N;
    int q = lane & 7, slot = lane >> 3;
    int qc = q < 6 ? q : 5;
    int s0 = rowptr[i0], e0 = rowptr[i0 + 1];
    int s1 = has1 ? rowptr[i1] : 0, e1 = has1 ? rowptr[i1 + 1] : 0;
    float a[8] = {0.f, 0.f, 0.f, 0.f, 0.f, 0.f, 0.f, 0.f};
    float c[8] = {0.f, 0.f, 0.f, 0.f, 0.f, 0.f, 0.f, 0.f};
    int p0 = s0 + slot, p1 = s1 + slot;
    while (p0 + 8 < e0 && p1 + 8 < e1) {
        int ca0 = ecol[p0], ca1 = ecol[p0 + 8];
        int cb0 = ecol[p1], cb1 = ecol[p1 + 8];
        half8v ha0 = *(const half8v*)(curs + (size_t)ca0 * D + qc * 8);
        half8v ha1 = *(const half8v*)(curs + (size_t)ca1 * D + qc * 8);
        half8v hb0 = *(const half8v*)(curs + (size_t)cb0 * D + qc * 8);
        half8v hb1 = *(const half8v*)(curs + (size_t)cb1 * D + qc * 8);
#pragma unroll
        for (int j = 0; j < 8; ++j) {
            a[j] += (float)ha0[j] + (float)ha1[j];
            c[j] += (float)hb0[j] + (float)hb1[j];
        }
        p0 += 16; p1 += 16;
    }
    while (p0 < e0) {
        int ca = ecol[p0];
        half8v ha = *(const half8v*)(curs + (size_t)ca * D + qc * 8);
#pragma unroll
        for (int j = 0; j < 8; ++j) a[j] += (float)ha[j];
        p0 += 8;
    }
    while (p1 < e1) {
        int cb = ecol[p1];
        half8v hb = *(const half8v*)(curs + (size_t)cb * D + qc * 8);
#pragma unroll
        for (int j = 0; j < 8; ++j) c[j] += (float)hb[j];
        p1 += 8;
    }
#pragma unroll
    for (int j = 0; j < 8; ++j) {
        a[j] += __shfl_xor(a[j], 8);  a[j] += __shfl_xor(a[j], 16); a[j] += __shfl_xor(a[j], 32);
        c[j] += __shfl_xor(c[j], 8);  c[j] += __shfl_xor(c[j], 16); c[j] += __shfl_xor(c[j], 32);
    }
    if (lane < 6) {
        float di0 = dinv[i0];
        half8v o, os;
#pragma unroll
        for (int j = 0; j < 8; ++j) {
            float t = -di0 * a[j];
            o[j] = (_Float16)t;
            os[j] = (_Float16)(di0 * t);
        }
        *(half8v*)(tx1 + (size_t)i0 * D + lane * 8) = o;
        *(half8v*)(tx1s + (size_t)i0 * D + lane * 8) = os;
        if (has1) {
            float di1 = dinv[i1];
            half8v o1, os1;
#pragma unroll
            for (int j = 0; j < 8; ++j) {
                float t = -di1 * c[j];
                o1[j] = (_Float16)t;
                os1[j] = (_Float16)(di1 * t);
            }
            *(half8v*)(tx1 + (size_t)i1 * D + lane * 8) = o1;
            *(half8v*)(tx1s + (size_t)i1 * D + lane * 8) = os1;
        }
    }
}

// tx2 = -2*dinv[i] * sum(tx1s[c]) - tx0
__global__ __launch_bounds__(256) void k_gather2(const _Float16* __restrict__ tx0, const _Float16* __restrict__ tx1s,
                                                 const int* __restrict__ rowptr, const int* __restrict__ ecol,
                                                 const float* __restrict__ dinv, _Float16* __restrict__ tx2, int N) {
    int lane = threadIdx.x & 63;
    int wv = (blockIdx.x * 256 + threadIdx.x) >> 6;
    int i0 = wv * 2;
    if (i0 >= N) return;
    int i1 = i0 + 1;
    bool has1 = i1 < N;
    int q = lane & 7, slot = lane >> 3;
    int qc = q < 6 ? q : 5;
    int s0 = rowptr[i0], e0 = rowptr[i0 + 1];
    int s1 = has1 ? rowptr[i1] : 0, e1 = has1 ? rowptr[i1 + 1] : 0;
    float a[8] = {0.f, 0.f, 0.f, 0.f, 0.f, 0.f, 0.f, 0.f};
    float c[8] = {0.f, 0.f, 0.f, 0.f, 0.f, 0.f, 0.f, 0.f};
    int p0 = s0 + slot, p1 = s1 + slot;
    while (p0 + 8 < e0 && p1 + 8 < e1) {
        int ca0 = ecol[p0], ca1 = ecol[p0 + 8];
        int cb0 = ecol[p1], cb1 = ecol[p1 + 8];
        half8v ha0 = *(const half8v*)(tx1s + (size_t)ca0 * D + qc * 8);
        half8v ha1 = *(const half8v*)(tx1s + (size_t)ca1 * D + qc * 8);
        half8v hb0 = *(const half8v*)(tx1s + (size_t)cb0 * D + qc * 8);
        half8v hb1 = *(const half8v*)(tx1s + (size_t)cb1 * D + qc * 8);
#pragma unroll
        for (int j = 0; j < 8; ++j) {
            a[j] += (float)ha0[j] + (float)ha1[j];
            c[j] += (float)hb0[j] + (float)hb1[j];
        }
        p0 += 16; p1 += 16;
    }
    while (p0 < e0) {
        int ca = ecol[p0];
        half8v ha = *(const half8v*)(tx1s + (size_t)ca * D + qc * 8);
#pragma unroll
        for (int j = 0; j < 8; ++j) a[j] += (float)ha[j];
        p0 += 8;
    }
    while (p1 < e1) {
        int cb = ecol[p1];
        half8v hb = *(const half8v*)(tx1s + (size_t)cb * D + qc * 8);
#pragma unroll
        for (int j = 0; j < 8; ++j) c[j] += (float)hb[j];
        p1 += 8;
    }
#pragma unroll
    for (int j = 0; j < 8; ++j) {
        a[j] += __shfl_xor(a[j], 8);  a[j] += __shfl_xor(a[j], 16); a[j] += __shfl_xor(a[j], 32);
        c[j] += __shfl_xor(c[j], 8);  c[j] += __shfl_xor(c[j], 16); c[j] += __shfl_xor(c[j], 32);
    }
    if (lane < 6) {
        float sc0 = -2.f * dinv[i0];
        half8v h0 = *(const half8v*)(tx0 + (size_t)i0 * D + lane * 8);
        half8v o;
#pragma unroll
        for (int j = 0; j < 8; ++j) o[j] = (_Float16)(sc0 * a[j] - (float)h0[j]);
        *(half8v*)(tx2 + (size_t)i0 * D + lane * 8) = o;
        if (has1) {
            float sc1 = -2.f * dinv[i1];
            half8v h1 = *(const half8v*)(tx0 + (size_t)i1 * D + lane * 8);
            half8v o1;
#pragma unroll
            for (int j = 0; j < 8; ++j) o1[j] = (_Float16)(sc1 * c[j] - (float)h1[j]);
            *(half8v*)(tx2 + (size_t)i1 * D + lane * 8) = o1;
        }
    }
}

// ---------------- dense: t = relu([tx0|tx1|tx2] @ W + b) ----------------

__global__ __launch_bounds__(256) void k_dense(const _Float16* __restrict__ tx0, const _Float16* __restrict__ tx1,
                                               const _Float16* __restrict__ tx2, const float* __restrict__ W,
                                               const float* __restrict__ b, _Float16* __restrict__ tbuf, int N) {
    __shared__ half2v WH2[72 * D];  // [kp][j] = (W[2kp][j], W[2kp+1][j]); 13824 B
    __shared__ float bL[D];
    for (int t = threadIdx.x; t < 72 * D; t += 256) {
        int kp = t / D, j = t % D;
        half2v w;
        w.x = (_Float16)W[(2 * kp) * D + j];
        w.y = (_Float16)W[(2 * kp + 1) * D + j];
        WH2[t] = w;
    }
    if (threadIdx.x < D) bL[threadIdx.x] = b[threadIdx.x];
    __syncthreads();

    int base = (blockIdx.x * 256 + threadIdx.x) * 2;
    if (base >= N) return;
    bool two = (base + 1) < N;

    const _Float16* rowsA[3] = {tx0 + (size_t)base * D, tx1 + (size_t)base * D, tx2 + (size_t)base * D};
    size_t off2 = two ? D : 0;

    float acc0[D], acc1[D];
#pragma unroll
    for (int j = 0; j < D; ++j) { acc0[j] = bL[j]; acc1[j] = bL[j]; }

    for (int s = 0; s < 3; ++s) {
        const half2v* xa = (const half2v*)rowsA[s];
        const half2v* xb = (const half2v*)(rowsA[s] + off2);
#pragma unroll 4
        for (int g = 0; g < 24; ++g) {
            half2v va = xa[g], vb = xb[g];
            int kp = s * 24 + g;
            const half8v* wr = (const half8v*)&WH2[kp * D];
#pragma unroll
            for (int jc = 0; jc < 12; ++jc) {
                half8v w = wr[jc];
                half2v w0; w0.x = w[0]; w0.y = w[1];
                half2v w1; w1.x = w[2]; w1.y = w[3];
                half2v w2; w2.x = w[4]; w2.y = w[5];
                half2v w3; w3.x = w[6]; w3.y = w[7];
                acc0[jc * 4 + 0] = FDOT2(va, w0, acc0[jc * 4 + 0]);
                acc0[jc * 4 + 1] = FDOT2(va, w1, acc0[jc * 4 + 1]);
                acc0[jc * 4 + 2] = FDOT2(va, w2, acc0[jc * 4 + 2]);
                acc0[jc * 4 + 3] = FDOT2(va, w3, acc0[jc * 4 + 3]);
                acc1[jc * 4 + 0] = FDOT2(vb, w0, acc1[jc * 4 + 0]);
                acc1[jc * 4 + 1] = FDOT2(vb, w1, acc1[jc * 4 + 1]);
                acc1[jc * 4 + 2] = FDOT2(vb, w2, acc1[jc * 4 + 2]);
                acc1[jc * 4 + 3] = FDOT2(vb, w3, acc1[jc * 4 + 3]);
            }
        }
    }

    _Float16* o0 = tbuf + (size_t)base * D;
#pragma unroll
    for (int jc = 0; jc < 12; ++jc) {
        half4v h;
        h.x = (_Float16)fmaxf(acc0[jc * 4 + 0], 0.f);
        h.y = (_Float16)fmaxf(acc0[jc * 4 + 1], 0.f);
        h.z = (_Float16)fmaxf(acc0[jc * 4 + 2], 0.f);
        h.w = (_Float16)fmaxf(acc0[jc * 4 + 3], 0.f);
        *(half4v*)(o0 + jc * 4) = h;
    }
    if (two) {
        _Float16* o1 = o0 + D;
#pragma unroll
        for (int jc = 0; jc < 12; ++jc) {
            half4v h;
            h.x = (_Float16)fmaxf(acc1[jc * 4 + 0], 0.f);
            h.y = (_Float16)fmaxf(acc1[jc * 4 + 1], 0.f);
            h.z = (_Float16)fmaxf(acc1[jc * 4 + 2], 0.f);
            h.w = (_Float16)fmaxf(acc1[jc * 4 + 3], 0.f);
            *(half4v*)(o1 + jc * 4) = h;
        }
    }
}

// ---------------- BN stats / finalize ----------------

__global__ __launch_bounds__(256) void k_bnstat(const _Float16* __restrict__ tbuf, float* __restrict__ bnstats, int N) {
    __shared__ float red[2 * D];
    if (threadIdx.x < 2 * D) red[threadIdx.x] = 0.f;
    __syncthreads();
    int tid = blockIdx.x * 256 + threadIdx.x;
    int q = tid % 12;
    int n0 = tid / 12;
    int stride = (gridDim.x * 256) / 12;
    float s0 = 0, s1 = 0, s2 = 0, s3 = 0, q0 = 0, q1 = 0, q2 = 0, q3 = 0;
    for (int n = n0; n < N; n += stride) {
        half4v h = *(const half4v*)(tbuf + (size_t)n * D + q * 4);
        float f0 = (float)h.x, f1 = (float)h.y, f2 = (float)h.z, f3 = (float)h.w;
        s0 += f0; s1 += f1; s2 += f2; s3 += f3;
        q0 += f0 * f0; q1 += f1 * f1; q2 += f2 * f2; q3 += f3 * f3;
    }
    atomicAdd(&red[q * 4 + 0], s0); atomicAdd(&red[q * 4 + 1], s1);
    atomicAdd(&red[q * 4 + 2], s2); atomicAdd(&red[q * 4 + 3], s3);
    atomicAdd(&red[D + q * 4 + 0], q0); atomicAdd(&red[D + q * 4 + 1], q1);
    atomicAdd(&red[D + q * 4 + 2], q2); atomicAdd(&red[D + q * 4 + 3], q3);
    __syncthreads();
    if (threadIdx.x < 2 * D) atomicAdd(&bnstats[threadIdx.x], red[threadIdx.x]);
}

__global__ __launch_bounds__(64) void k_bnfin(float* __restrict__ bnstats, const float* __restrict__ gamma,
                                              const float* __restrict__ beta, float* __restrict__ ss, float Ninv) {
    int t = threadIdx.x;
    if (t < D) {
        float mean = bnstats[t] * Ninv;
        float var = bnstats[D + t] * Ninv - mean * mean;
        var = fmaxf(var, 0.f);
        float sc = gamma[t] * rsqrtf(var + BN_EPS);
        ss[t] = sc;
        ss[D + t] = beta[t] - mean * sc;
        bnstats[t] = 0.f;
        bnstats[D + t] = 0.f;
    }
}

// ---------------- pool ----------------
// out = BN(max/min over neighbors), outs = dinv[i]*out; 2 nodes per wave

__global__ __launch_bounds__(256) void k_pool(const _Float16* __restrict__ tbuf, const int* __restrict__ rowptr,
                                              const int* __restrict__ ecol, const float* __restrict__ ss,
                                              const float* __restrict__ dinv, _Float16* __restrict__ outh,
                                              _Float16* __restrict__ outs, int N) {
    int lane = threadIdx.x & 63;
    int wv = (blockIdx.x * 256 + threadIdx.x) >> 6;
    int i0 = wv * 2;
    if (i0 >= N) return;
    int i1 = i0 + 1;
    bool has1 = i1 < N;
    int q = lane & 7, slot = lane >> 3;
    int qc = q < 6 ? q : 5;
    int s0 = rowptr[i0], e0 = rowptr[i0 + 1];
    int s1 = has1 ? rowptr[i1] : 0, e1 = has1 ? rowptr[i1 + 1] : 0;
    float mxa[8], mna[8], mxb[8], mnb[8];
#pragma unroll
    for (int j = 0; j < 8; ++j) {
        mxa[j] = -3.4e38f; mna[j] = 3.4e38f;
        mxb[j] = -3.4e38f; mnb[j] = 3.4e38f;
    }
    int p0 = s0 + slot, p1 = s1 + slot;
    while (p0 + 8 < e0 && p1 + 8 < e1) {
        int ca0 = ecol[p0], ca1 = ecol[p0 + 8];
        int cb0 = ecol[p1], cb1 = ecol[p1 + 8];
        half8v ha0 = *(const half8v*)(tbuf + (size_t)ca0 * D + qc * 8);
        half8v ha1 = *(const half8v*)(tbuf + (size_t)ca1 * D + qc * 8);
        half8v hb0 = *(const half8v*)(tbuf + (size_t)cb0 * D + qc * 8);
        half8v hb1 = *(const half8v*)(tbuf + (size_t)cb1 * D + qc * 8);
#pragma unroll
        for (int j = 0; j < 8; ++j) {
            float f0 = (float)ha0[j], f1 = (float)ha1[j];
            float g0 = (float)hb0[j], g1 = (float)hb1[j];
            mxa[j] = fmaxf(mxa[j], fmaxf(f0, f1)); mna[j] = fminf(mna[j], fminf(f0, f1));
            mxb[j] = fmaxf(mxb[j], fmaxf(g0, g1)); mnb[j] = fminf(mnb[j], fminf(g0, g1));
        }
        p0 += 16; p1 += 16;
    }
    while (p0 < e0) {
        int ca = ecol[p0];
        half8v ha = *(const half8v*)(tbuf + (size_t)ca * D + qc * 8);
#pragma unroll
        for (int j = 0; j < 8; ++j) {
            float f = (float)ha[j];
            mxa[j] = fmaxf(mxa[j], f); mna[j] = fminf(mna[j], f);
        }
        p0 += 8;
    }
    while (p1 < e1) {
        int cb = ecol[p1];
        half8v hb = *(const half8v*)(tbuf + (size_t)cb * D + qc * 8);
#pragma unroll
        for (int j = 0; j < 8; ++j) {
            float f = (float)hb[j];
            mxb[j] = fmaxf(mxb[j], f); mnb[j] = fminf(mnb[j], f);
        }
        p1 += 8;
    }
#pragma unroll
    for (int j = 0; j < 8; ++j) {
        mxa[j] = fmaxf(mxa[j], __shfl_xor(mxa[j], 8));
        mxa[j] = fmaxf(mxa[j], __shfl_xor(mxa[j], 16));
        mxa[j] = fmaxf(mxa[j], __shfl_xor(mxa[j], 32));
        mna[j] = fminf(mna[j], __shfl_xor(mna[j], 8));
        mna[j] = fminf(mna[j], __shfl_xor(mna[j], 16));
        mna[j] = fminf(mna[j], __shfl_xor(mna[j], 32));
        mxb[j] = fmaxf(mxb[j], __shfl_xor(mxb[j], 8));
        mxb[j] = fmaxf(mxb[j], __shfl_xor(mxb[j], 16));
        mxb[j] = fmaxf(mxb[j], __shfl_xor(mxb[j], 32));
        mnb[j] = fminf(mnb[j], __shfl_xor(mnb[j], 8));
        mnb[j] = fminf(mnb[j], __shfl_xor(mnb[j], 16));
        mnb[j] = fminf(mnb[j], __shfl_xor(mnb[j], 32));
    }
    if (lane < 6) {
        {
            float di = dinv[i0];
            half8v o, os;
            if (s0 == e0) {
#pragma unroll
                for (int j = 0; j < 8; ++j) { o[j] = (_Float16)0.f; os[j] = (_Float16)0.f; }
            } else {
#pragma unroll
                for (int j = 0; j < 8; ++j) {
                    float scj = ss[lane * 8 + j];
                    float shj = ss[D + lane * 8 + j];
                    float v = (scj >= 0.f) ? scj * mxa[j] + shj : scj * mna[j] + shj;
                    o[j] = (_Float16)v;
                    os[j] = (_Float16)(di * v);
                }
            }
            *(half8v*)(outh + (size_t)i0 * D + lane * 8) = o;
            *(half8v*)(outs + (size_t)i0 * D + lane * 8) = os;
        }
        if (has1) {
            float di = dinv[i1];
            half8v o, os;
            if (s1 == e1) {
#pragma unroll
                for (int j = 0; j < 8; ++j) { o[j] = (_Float16)0.f; os[j] = (_Float16)0.f; }
            } else {
#pragma unroll
                for (int j = 0; j < 8; ++j) {
                    float scj = ss[lane * 8 + j];
                    float shj = ss[D + lane * 8 + j];
                    float v = (scj >= 0.f) ? scj * mxb[j] + shj : scj * mnb[j] + shj;
                    o[j] = (_Float16)v;
                    os[j] = (_Float16)(di * v);
                }
            }
            *(half8v*)(outh + (size_t)i1 * D + lane * 8) = o;
            *(half8v*)(outs + (size_t)i1 * D + lane * 8) = os;
        }
    }
}

// ---------------- final pooling + MLP ----------------

__global__ __launch_bounds__(256) void k_gpool(const _Float16* __restrict__ outh, const int* __restrict__ batch,
                                               float* __restrict__ g, int N, int chunk) {
    int lane = threadIdx.x & 63;
    int wid = (blockIdx.x * 256 + threadIdx.x) >> 6;
    int start = wid * chunk;
    if (start >= N || lane >= 12) return;
    int end = start + chunk;
    if (end > N) end = N;
    int curb = batch[start];
    float a0 = 0.f, a1 = 0.f, a2 = 0.f, a3 = 0.f;
    for (int i = start; i < end; ++i) {
        int bi = batch[i];
        if (bi != curb) {
            atomicAdd(&g[curb * D + lane * 4 + 0], a0); atomicAdd(&g[curb * D + lane * 4 + 1], a1);
            atomicAdd(&g[curb * D + lane * 4 + 2], a2); atomicAdd(&g[curb * D + lane * 4 + 3], a3);
            curb = bi; a0 = a1 = a2 = a3 = 0.f;
        }
        half4v h = *(const half4v*)(outh + (size_t)i * D + lane * 4);
        a0 += (float)h.x; a1 += (float)h.y; a2 += (float)h.z; a3 += (float)h.w;
    }
    atomicAdd(&g[curb * D + lane * 4 + 0], a0); atomicAdd(&g[curb * D + lane * 4 + 1], a1);
    atomicAdd(&g[curb * D + lane * 4 + 2], a2); atomicAdd(&g[curb * D + lane * 4 + 3], a3);
}

__global__ __launch_bounds__(256) void k_mlp(const float* __restrict__ g, const float* __restrict__ W1,
                                             const float* __restrict__ b1, const float* __restrict__ W2,
                                             const float* __restrict__ b2, float* __restrict__ out) {
    __shared__ float gL[GNUM * D];
    __shared__ float hL[GNUM * HDIM];
    __shared__ float W1L[D * HDIM];
    int t = threadIdx.x;
    for (int i = t; i < GNUM * D; i += 256) gL[i] = g[i];
    for (int i = t; i < D * HDIM; i += 256) W1L[i] = W1[i];
    __syncthreads();
    for (int i = t; i < GNUM * HDIM; i += 256) {
        int gi = i >> 7, hj = i & 127;
        float a = b1[hj];
        for (int k = 0; k < D; ++k) a += gL[gi * D + k] * W1L[k * HDIM + hj];
        hL[i] = fmaxf(a, 0.f);
    }
    __syncthreads();
    for (int i = t; i < GNUM * ODIM; i += 256) {
        int gi = i / ODIM, oj = i % ODIM;
        float a = b2[oj];
        for (int k = 0; k < HDIM; ++k) a += hL[gi * HDIM + k] * W2[k * ODIM + oj];
        out[i] = a;
    }
}

// ---------------- launch ----------------

extern "C" void kernel_launch(void* const* d_in, const int* in_sizes, int n_in,
                              void* d_out, int out_size, void* d_ws, size_t ws_size,
                              hipStream_t stream) {
    const float* x     = (const float*)d_in[0];
    const int*   ei    = (const int*)d_in[1];
    const int*   batch = (const int*)d_in[2];
    const float* W     = (const float*)d_in[4];
    const float* b     = (const float*)d_in[5];
    const float* gamma = (const float*)d_in[6];
    const float* beta  = (const float*)d_in[7];
    const float* W1    = (const float*)d_in[8];
    const float* b1    = (const float*)d_in[9];
    const float* W2    = (const float*)d_in[10];
    const float* b2    = (const float*)d_in[11];

    int N = in_sizes[0] / D;
    int E = in_sizes[1] / 2;
    const int* row = ei;
    const int* col = ei + E;

    char* w = (char*)d_ws;
    auto alloc = [&](size_t bytes) { char* p = w; w += (bytes + 255) & ~(size_t)255; return p; };
    int*       deg     = (int*)alloc((size_t)N * 4);
    float*     dinv    = (float*)alloc((size_t)N * 4);
    int*       fillc   = (int*)alloc((size_t)N * 4);
    int*       incl    = (int*)alloc((size_t)N * 4);
    int*       bsum    = (int*)alloc(4096);
    int*       rowptr  = (int*)alloc((size_t)(N + 1) * 4);
    int*       ecol    = (int*)alloc((size_t)E * 4);
    _Float16*  xh      = (_Float16*)alloc((size_t)N * D * 2 + 64);
    _Float16*  xs      = (_Float16*)alloc((size_t)N * D * 2 + 64);
    _Float16*  tx1h    = (_Float16*)alloc((size_t)N * D * 2 + 64);
    _Float16*  tx1s    = (_Float16*)alloc((size_t)N * D * 2 + 64);
    _Float16*  tx2h    = (_Float16*)alloc((size_t)N * D * 2 + 64);
    _Float16*  tbufh   = (_Float16*)alloc((size_t)N * D * 2 + 64);
    _Float16*  outh    = (_Float16*)alloc((size_t)N * D * 2 + 64);
    _Float16*  outs    = (_Float16*)alloc((size_t)N * D * 2 + 64);
    float*     bnstats = (float*)alloc(2 * D * 4);
    float*     ss      = (float*)alloc(2 * D * 4);
    float*     g       = (float*)alloc((size_t)GNUM * D * 4);

    hipMemsetAsync(deg, 0, (size_t)N * 4, stream);
    hipMemsetAsync(fillc, 0, (size_t)N * 4, stream);
    hipMemsetAsync(bnstats, 0, 2 * D * 4, stream);
    hipMemsetAsync(g, 0, (size_t)GNUM * D * 4, stream);

    int nbE = (E + 255) / 256;
    int nbN = (N + 255) / 256;

    k_deg<<<nbE, 256, 0, stream>>>(row, deg, E);
    k_dinv<<<nbN, 256, 0, stream>>>(deg, dinv, N);
    k_scan1<<<nbN, 256, 0, stream>>>(deg, incl, bsum, N);
    k_scan2<<<1, 512, 0, stream>>>(bsum, nbN);
    k_scan3<<<nbN, 256, 0, stream>>>(incl, bsum, rowptr, N);
    k_fill<<<nbE, 256, 0, stream>>>(row, col, rowptr, fillc, ecol, E);
    int n4 = N * D / 4;
    k_cvt<<<(n4 + 255) / 256, 256, 0, stream>>>(x, dinv, xh, xs, n4);

    int nwave2 = (N + 1) / 2;                      // 2 nodes per wave
    int nbWave2 = (nwave2 * 64 + 255) / 256;
    int nbDense = ((N + 1) / 2 + 255) / 256;
    const _Float16* curh = xh;
    const _Float16* curs = xs;
    for (int step = 0; step < 5; ++step) {
        k_lhat<<<nbWave2, 256, 0, stream>>>(curs, rowptr, ecol, dinv, tx1h, tx1s, N);
        k_gather2<<<nbWave2, 256, 0, stream>>>(curh, tx1s, rowptr, ecol, dinv, tx2h, N);
        k_dense<<<nbDense, 256, 0, stream>>>(curh, tx1h, tx2h, W, b, tbufh, N);
        k_bnstat<<<120, 256, 0, stream>>>(tbufh, bnstats, N);
        k_bnfin<<<1, 64, 0, stream>>>(bnstats, gamma, beta, ss, 1.f / (float)N);
        k_pool<<<nbWave2, 256, 0, stream>>>(tbufh, rowptr, ecol, ss, dinv, outh, outs, N);
        curh = outh;
        curs = outs;
    }

    int chunk = 32;
    int nwaves = (N + chunk - 1) / chunk;
    int nbG = (nwaves * 64 + 255) / 256;
    k_gpool<<<nbG, 256, 0, stream>>>(outh, batch, g, N, chunk);
    k_mlp<<<1, 256, 0, stream>>>(g, W1, b1, W2, b2, (float*)d_out);
}